// Round 9
// baseline (336.461 us; speedup 1.0000x reference)
//
#include <hip/hip_runtime.h>
#include <cstdint>
#include <math.h>

#define CF4(p) (*reinterpret_cast<const float4*>(p))
#define F4(p)  (*reinterpret_cast<float4*>(p))

typedef __attribute__((ext_vector_type(8))) short bf16x8;
typedef __attribute__((ext_vector_type(4))) float f32x4;

__device__ __forceinline__ unsigned short f2bf(float x) {
  union { float f; unsigned int u; } v; v.f = x;
  unsigned int r = v.u + 0x7FFF + ((v.u >> 16) & 1);
  return (unsigned short)(r >> 16);
}

// swizzled LDS element index for [row][64 bf16] tiles (128B rows):
// elem col ^= ((row&7)<<3)  <=>  byte ^= ((row&7)<<4)
__device__ __forceinline__ int swz(int row, int col) {
  return row * 64 + (col ^ ((row & 7) << 3));
}

__device__ __forceinline__ void gload_lds16(const void* g, void* lds) {
  __builtin_amdgcn_global_load_lds(
      (const __attribute__((address_space(1))) void*)g,
      (__attribute__((address_space(3))) void*)lds, 16, 0, 0);
}

// ---------------------------------------------------------------------------
// fused fp32 -> bf16 convert for all 5 tensors (1 launch)
// ---------------------------------------------------------------------------
__global__ __launch_bounds__(256) void cvt_all_kernel(
    const float* __restrict__ src,   unsigned short* __restrict__ src_bf,
    const float* __restrict__ qkvw,  unsigned short* __restrict__ qkvw_bf,
    const float* __restrict__ outw,  unsigned short* __restrict__ outw_bf,
    const float* __restrict__ w1,    unsigned short* __restrict__ w1_bf,
    const float* __restrict__ w2,    unsigned short* __restrict__ w2_bf)
{
  int i = blockIdx.x * 256 + threadIdx.x;
  const float* s; unsigned short* d;
  if      (i < 524288) { s = src;  d = src_bf;                        }
  else if (i < 622592) { s = qkvw; d = qkvw_bf; i -= 524288;          }
  else if (i < 655360) { s = outw; d = outw_bf; i -= 622592;          }
  else if (i < 786432) { s = w1;   d = w1_bf;   i -= 655360;          }
  else if (i < 917504) { s = w2;   d = w2_bf;   i -= 786432;          }
  else return;
  float4 a = CF4(&s[i * 8]), b = CF4(&s[i * 8 + 4]);
  union { bf16x8 v; unsigned short u[8]; } w;
  w.u[0] = f2bf(a.x); w.u[1] = f2bf(a.y); w.u[2] = f2bf(a.z); w.u[3] = f2bf(a.w);
  w.u[4] = f2bf(b.x); w.u[5] = f2bf(b.y); w.u[6] = f2bf(b.z); w.u[7] = f2bf(b.w);
  *reinterpret_cast<bf16x8*>(&d[i * 8]) = w.v;
}

// ---------------------------------------------------------------------------
// bf16 MFMA GEMM, double-buffered, tile 128 x BNT (BNT=128 or 64).
// NEW: swapped MFMA operands -> C^T fragments: lane holds row m = ..+lr
// (fixed) and 4 consecutive cols n = ..+g*4+reg per fragment. Epilogue is
// 4*NJ coalesced 16B/8B vector stores + float4 bias/residual loads
// (was 64 scalar stores) -- cuts the ~30% epilogue overhead at K=512.
// ---------------------------------------------------------------------------
template<int BNT, int BIAS, int RELU, int RES, int OBF>
__global__ __launch_bounds__(256, 2) void bgemm_kernel(
    void* __restrict__ Cv, const unsigned short* __restrict__ A,
    const unsigned short* __restrict__ W, const float* __restrict__ bias,
    const float* __restrict__ R, int M, int N, int K)
{
  constexpr int NJ = BNT / 32;
  __shared__ __align__(16) unsigned short As[2][128 * 64];
  __shared__ __align__(16) unsigned short Ws[2][BNT * 64];

  const int t    = threadIdx.x;
  const int lane = t & 63, wid = t >> 6;
  const int g    = lane >> 4, lr = lane & 15;
  const int wm   = wid >> 1,  wn = wid & 1;
  const int m0   = blockIdx.y * 128, n0 = blockIdx.x * BNT;

  const int sr8 = lane >> 3;
  const int sc  = (lane & 7) ^ sr8;
  const unsigned short* Ag = A + (size_t)(m0 + sr8) * K + sc * 8;
  const unsigned short* Wg = W + (size_t)(n0 + sr8) * K + sc * 8;

  f32x4 acc[4][NJ];
#pragma unroll
  for (int mi = 0; mi < 4; ++mi)
#pragma unroll
    for (int nj = 0; nj < NJ; ++nj)
      acc[mi][nj] = (f32x4){0.f, 0.f, 0.f, 0.f};

#define STAGE_G(buf, k0)                                                   \
  {                                                                        \
    _Pragma("unroll")                                                      \
    for (int i = 0; i < 4; ++i) {                                          \
      const int rb = wid * 32 + i * 8;                                     \
      gload_lds16(Ag + (size_t)rb * K + (k0), (void*)&As[buf][rb * 64]);   \
    }                                                                      \
    _Pragma("unroll")                                                      \
    for (int i = 0; i < BNT / 32; ++i) {                                   \
      const int rb = wid * (BNT / 4) + i * 8;                              \
      gload_lds16(Wg + (size_t)rb * K + (k0), (void*)&Ws[buf][rb * 64]);   \
    }                                                                      \
  }

  STAGE_G(0, 0);
  __syncthreads();

  const int nk = K >> 6;
  for (int kt = 0; kt < nk; ++kt) {
    const int cur = kt & 1;
    if (kt + 1 < nk) STAGE_G(cur ^ 1, (kt + 1) * 64);
#pragma unroll
    for (int ks = 0; ks < 2; ++ks) {
      bf16x8 af[4], bfr[NJ];
#pragma unroll
      for (int mi = 0; mi < 4; ++mi) {
        const int row = wm * 64 + mi * 16 + lr;
        af[mi] = *reinterpret_cast<const bf16x8*>(
            &As[cur][row * 64 + (((ks * 4 + g) ^ (row & 7)) * 8)]);
      }
#pragma unroll
      for (int nj = 0; nj < NJ; ++nj) {
        const int row = wn * (BNT / 2) + nj * 16 + lr;
        bfr[nj] = *reinterpret_cast<const bf16x8*>(
            &Ws[cur][row * 64 + (((ks * 4 + g) ^ (row & 7)) * 8)]);
      }
#pragma unroll
      for (int mi = 0; mi < 4; ++mi)
#pragma unroll
        for (int nj = 0; nj < NJ; ++nj)
          acc[mi][nj] = __builtin_amdgcn_mfma_f32_16x16x32_bf16(
              bfr[nj], af[mi], acc[mi][nj], 0, 0, 0);   // SWAPPED operands
    }
    __syncthreads();
  }
#undef STAGE_G

  // epilogue (C^T frags): r = m0+wm*64+mi*16+lr; c0 = n0+wn*(BNT/2)+nj*16+g*4
#pragma unroll
  for (int mi = 0; mi < 4; ++mi) {
    const int r = m0 + wm * 64 + mi * 16 + lr;
#pragma unroll
    for (int nj = 0; nj < NJ; ++nj) {
      const int c0 = n0 + wn * (BNT / 2) + nj * 16 + g * 4;
      float4 v = make_float4(acc[mi][nj][0], acc[mi][nj][1],
                             acc[mi][nj][2], acc[mi][nj][3]);
      if (BIAS) {
        float4 bb = CF4(&bias[c0]);
        v.x += bb.x; v.y += bb.y; v.z += bb.z; v.w += bb.w;
      }
      if (RES) {
        float4 rr = CF4(&R[(size_t)r * N + c0]);
        v.x += rr.x; v.y += rr.y; v.z += rr.z; v.w += rr.w;
      }
      if (RELU) {
        v.x = fmaxf(v.x, 0.f); v.y = fmaxf(v.y, 0.f);
        v.z = fmaxf(v.z, 0.f); v.w = fmaxf(v.w, 0.f);
      }
      if (OBF) {
        unsigned int w0, w1;
        asm("v_cvt_pk_bf16_f32 %0, %1, %2" : "=v"(w0) : "v"(v.x), "v"(v.y));
        asm("v_cvt_pk_bf16_f32 %0, %1, %2" : "=v"(w1) : "v"(v.z), "v"(v.w));
        *reinterpret_cast<uint2*>(
            &((unsigned short*)Cv)[(size_t)r * N + c0]) = make_uint2(w0, w1);
      } else {
        F4(&((float*)Cv)[(size_t)r * N + c0]) = v;
      }
    }
  }
}

// ---------------------------------------------------------------------------
// Flash attention: REVERTED to R7 structure (QBLK=128, 4 waves, 121.7 us).
// bf16, MFMA, double-buffered K/V, swapped QK^T, fixed-max softmax,
// cvt_pk P-conversion, lane-local row-sums, s_setprio around MFMA.
// ---------------------------------------------------------------------------
__global__ __launch_bounds__(256, 2) void attn_kernel(
    unsigned short* __restrict__ O, const unsigned short* __restrict__ qkv)
{
  const int Bb = 2, LD = 1536, DM = 512;
  const int qt = blockIdx.x;
  const int nh = blockIdx.y;
  const int b = nh >> 3, h = nh & 7;
  const int cq = h * 64, ck = 512 + h * 64, cv = 1024 + h * 64;

  __shared__ __align__(16) unsigned short Ks [2][64 * 64];  // 16 KB [kk][k]
  __shared__ __align__(16) unsigned short Vts[2][64 * 64];  // 16 KB [d][kk]
  __shared__ __align__(16) unsigned short Ps [128 * 64];    // 16 KB [q][kk]

  const int t    = threadIdx.x;
  const int lane = t & 63;
  const int wid  = t >> 6;
  const int g    = lane >> 4;
  const int lr   = lane & 15;
  const int wq0  = wid * 32;

  bf16x8 qf[2][2];
#pragma unroll
  for (int mi = 0; mi < 2; ++mi)
#pragma unroll
    for (int kq = 0; kq < 2; ++kq)
      qf[mi][kq] = *reinterpret_cast<const bf16x8*>(
          &qkv[((size_t)(qt * 128 + wq0 + mi * 16 + lr) * Bb + b) * LD
               + cq + kq * 32 + g * 8]);

  f32x4 o_acc[2][4];
  float lsum[2] = {0.f, 0.f};
#pragma unroll
  for (int mi = 0; mi < 2; ++mi)
#pragma unroll
    for (int dj = 0; dj < 4; ++dj)
      o_acc[mi][dj] = (f32x4){0.f, 0.f, 0.f, 0.f};

  const int sr8 = lane >> 3;
  const int scK = (lane & 7) ^ sr8;
  const int vD0 = wid * 8;
  const int vSr = lane;

#define STAGE_K(buf, kt)                                               \
  {                                                                    \
    _Pragma("unroll")                                                  \
    for (int i = 0; i < 2; ++i) {                                      \
      const int rb = wid * 16 + i * 8;                                 \
      gload_lds16(&qkv[((size_t)((kt) * 64 + rb + sr8) * Bb + b) * LD  \
                       + ck + scK * 8],                                \
                  (void*)&Ks[buf][rb * 64]);                           \
    }                                                                  \
  }
#define LOAD_V(kt)                                                     \
  {                                                                    \
    _Pragma("unroll")                                                  \
    for (int p = 0; p < 2; ++p)                                        \
      vr[p] = *reinterpret_cast<const bf16x8*>(                        \
          &qkv[((size_t)((kt) * 64 + vSr) * Bb + b) * LD + cv          \
               + vD0 + p * 32]);                                       \
  }
#define WRITE_V(buf)                                                   \
  {                                                                    \
    _Pragma("unroll")                                                  \
    for (int p = 0; p < 2; ++p) {                                      \
      const int d0 = vD0 + p * 32;                                     \
      union { bf16x8 v; unsigned short u[8]; } w;                      \
      w.v = vr[p];                                                     \
      _Pragma("unroll")                                                \
      for (int j = 0; j < 8; ++j)                                      \
        Vts[buf][swz(d0 + j, vSr)] = w.u[j];                           \
    }                                                                  \
  }

  bf16x8 vr[2];
  STAGE_K(0, 0);
  LOAD_V(0);
  WRITE_V(0);
  __syncthreads();

  for (int kt = 0; kt < 64; ++kt) {
    const int cur = kt & 1;
    const bool hasNext = (kt < 63);
    if (hasNext) { STAGE_K(cur ^ 1, kt + 1); LOAD_V(kt + 1); }

    // ---- S^T = K Q^T ----
    f32x4 sfT[2][4];
#pragma unroll
    for (int mi = 0; mi < 2; ++mi)
#pragma unroll
      for (int nj = 0; nj < 4; ++nj)
        sfT[mi][nj] = (f32x4){0.f, 0.f, 0.f, 0.f};
    __builtin_amdgcn_s_setprio(1);
#pragma unroll
    for (int nj = 0; nj < 4; ++nj) {
#pragma unroll
      for (int kq = 0; kq < 2; ++kq) {
        bf16x8 ak = *reinterpret_cast<const bf16x8*>(
            &Ks[cur][swz(nj * 16 + lr, kq * 32 + g * 8)]);
        sfT[0][nj] = __builtin_amdgcn_mfma_f32_16x16x32_bf16(
            ak, qf[0][kq], sfT[0][nj], 0, 0, 0);
        sfT[1][nj] = __builtin_amdgcn_mfma_f32_16x16x32_bf16(
            ak, qf[1][kq], sfT[1][nj], 0, 0, 0);
      }
    }
    __builtin_amdgcn_s_setprio(0);

    // ---- fixed-max softmax, lane-local row q = wq0 + mi*16 + lr ----
#pragma unroll
    for (int mi = 0; mi < 2; ++mi) {
      const int qrow = wq0 + mi * 16 + lr;
#pragma unroll
      for (int nj = 0; nj < 4; ++nj) {
        const float p0 = __expf(sfT[mi][nj][0]);
        const float p1 = __expf(sfT[mi][nj][1]);
        const float p2 = __expf(sfT[mi][nj][2]);
        const float p3 = __expf(sfT[mi][nj][3]);
        lsum[mi] += (p0 + p1) + (p2 + p3);
        unsigned int w0, w1;
        asm("v_cvt_pk_bf16_f32 %0, %1, %2" : "=v"(w0) : "v"(p0), "v"(p1));
        asm("v_cvt_pk_bf16_f32 %0, %1, %2" : "=v"(w1) : "v"(p2), "v"(p3));
        *reinterpret_cast<uint2*>(&Ps[swz(qrow, nj * 16 + g * 4)]) =
            make_uint2(w0, w1);
      }
    }

    // ---- O += P V ----
    __builtin_amdgcn_s_setprio(1);
#pragma unroll
    for (int kks = 0; kks < 2; ++kks) {
      bf16x8 pa0 = *reinterpret_cast<const bf16x8*>(
          &Ps[swz(wq0 +  0 + lr, kks * 32 + g * 8)]);
      bf16x8 pa1 = *reinterpret_cast<const bf16x8*>(
          &Ps[swz(wq0 + 16 + lr, kks * 32 + g * 8)]);
#pragma unroll
      for (int dj = 0; dj < 4; ++dj) {
        bf16x8 vb = *reinterpret_cast<const bf16x8*>(
            &Vts[cur][swz(dj * 16 + lr, kks * 32 + g * 8)]);
        o_acc[0][dj] = __builtin_amdgcn_mfma_f32_16x16x32_bf16(
            pa0, vb, o_acc[0][dj], 0, 0, 0);
        o_acc[1][dj] = __builtin_amdgcn_mfma_f32_16x16x32_bf16(
            pa1, vb, o_acc[1][dj], 0, 0, 0);
      }
    }
    __builtin_amdgcn_s_setprio(0);

    if (hasNext) WRITE_V(cur ^ 1);
    __syncthreads();
  }
#undef STAGE_K
#undef LOAD_V
#undef WRITE_V

  // ---- final: reduce row-sums, broadcast, store bf16 ----
#pragma unroll
  for (int mi = 0; mi < 2; ++mi) {
    float rs = lsum[mi];
    rs += __shfl_xor(rs, 16);
    rs += __shfl_xor(rs, 32);
#pragma unroll
    for (int reg = 0; reg < 4; ++reg) {
      const float rsq = __shfl(rs, (lane & 48) + g * 4 + reg);
      const float inv = 1.f / rsq;
      const int q = qt * 128 + wq0 + mi * 16 + g * 4 + reg;
#pragma unroll
      for (int dj = 0; dj < 4; ++dj)
        O[((size_t)q * Bb + b) * DM + h * 64 + dj * 16 + lr] =
            f2bf(o_acc[mi][dj][reg] * inv);
    }
  }
}

// ---------------------------------------------------------------------------
// LayerNorm D=512; optional bf16 side output
// ---------------------------------------------------------------------------
template<int WBF>
__global__ __launch_bounds__(256) void ln_kernel(
    float* __restrict__ out, unsigned short* __restrict__ obf,
    const float* __restrict__ in, const float* __restrict__ g,
    const float* __restrict__ bb)
{
  const int w = threadIdx.x >> 6, lane = threadIdx.x & 63;
  const size_t row = (size_t)blockIdx.x * 4 + w;
  const float* xr = in + row * 512;
  float4 v0 = CF4(&xr[lane * 4]);
  float4 v1 = CF4(&xr[256 + lane * 4]);
  float s = v0.x + v0.y + v0.z + v0.w + v1.x + v1.y + v1.z + v1.w;
  float q = v0.x*v0.x + v0.y*v0.y + v0.z*v0.z + v0.w*v0.w
          + v1.x*v1.x + v1.y*v1.y + v1.z*v1.z + v1.w*v1.w;
#pragma unroll
  for (int off = 1; off < 64; off <<= 1) {
    s += __shfl_xor(s, off);
    q += __shfl_xor(q, off);
  }
  const float mu  = s * (1.f / 512.f);
  const float var = q * (1.f / 512.f) - mu * mu;
  const float rst = rsqrtf(var + 1e-5f);
  float4 g0 = CF4(&g[lane * 4]),  g1 = CF4(&g[256 + lane * 4]);
  float4 b0 = CF4(&bb[lane * 4]), b1 = CF4(&bb[256 + lane * 4]);
  float* orow = out + row * 512;
  float4 o0, o1;
  o0.x = (v0.x - mu) * rst * g0.x + b0.x;
  o0.y = (v0.y - mu) * rst * g0.y + b0.y;
  o0.z = (v0.z - mu) * rst * g0.z + b0.z;
  o0.w = (v0.w - mu) * rst * g0.w + b0.w;
  o1.x = (v1.x - mu) * rst * g1.x + b1.x;
  o1.y = (v1.y - mu) * rst * g1.y + b1.y;
  o1.z = (v1.z - mu) * rst * g1.z + b1.z;
  o1.w = (v1.w - mu) * rst * g1.w + b1.w;
  F4(&orow[lane * 4]) = o0;
  F4(&orow[256 + lane * 4]) = o1;
  if (WBF) {
    unsigned short* brow = obf + row * 512;
    ushort4 u0 = make_ushort4(f2bf(o0.x), f2bf(o0.y), f2bf(o0.z), f2bf(o0.w));
    ushort4 u1 = make_ushort4(f2bf(o1.x), f2bf(o1.y), f2bf(o1.z), f2bf(o1.w));
    *reinterpret_cast<ushort4*>(&brow[lane * 4]) = u0;
    *reinterpret_cast<ushort4*>(&brow[256 + lane * 4]) = u1;
  }
}

// ---------------------------------------------------------------------------
extern "C" void kernel_launch(void* const* d_in, const int* in_sizes, int n_in,
                              void* d_out, int out_size, void* d_ws, size_t ws_size,
                              hipStream_t stream)
{
  const float* src   = (const float*)d_in[0];
  const float* qkv_w = (const float*)d_in[1];
  const float* qkv_b = (const float*)d_in[2];
  const float* out_w = (const float*)d_in[3];
  const float* w1    = (const float*)d_in[4];
  const float* b1    = (const float*)d_in[5];
  const float* w2    = (const float*)d_in[6];
  const float* b2    = (const float*)d_in[7];
  const float* ln1g  = (const float*)d_in[8];
  const float* ln1b  = (const float*)d_in[9];
  const float* ln2g  = (const float*)d_in[10];
  const float* ln2b  = (const float*)d_in[11];
  float* out = (float*)d_out;

  const int M = 8192;

  char* ws = (char*)d_ws;
  unsigned short* qkv_bf  = (unsigned short*)(ws + 0);         // 25165824
  unsigned short* attn_bf = (unsigned short*)(ws + 25165824);  //  8388608
  unsigned short* h_bf    = (unsigned short*)(ws + 0);         // 33554432 (reuse)
  float*          y       = (float*)(ws + 33554432);           // 16777216
  float*          z       = (float*)(ws + 33554432);           // (reuse y)
  float*          x       = (float*)(ws + 50331648);           // 16777216
  unsigned short* x_bf    = (unsigned short*)(ws + 67108864);  //  8388608
  unsigned short* src_bf  = (unsigned short*)(ws + 75497472);  //  8388608
  unsigned short* wqkv_bf = (unsigned short*)(ws + 83886080);  //  1572864
  unsigned short* wout_bf = (unsigned short*)(ws + 85458944);  //   524288
  unsigned short* w1_bf   = (unsigned short*)(ws + 85983232);  //  2097152
  unsigned short* w2_bf   = (unsigned short*)(ws + 88080384);  //  2097152
  if (ws_size < (size_t)90177536) return;

  dim3 blk(256);

  // 0. all fp32 -> bf16 conversions (1 launch)
  cvt_all_kernel<<<dim3(3584), blk, 0, stream>>>(
      src, src_bf, qkv_w, wqkv_bf, out_w, wout_bf, w1, w1_bf, w2, w2_bf);

  // 1. qkv = src @ qkv_w^T + qkv_b   (bf16 out)
  bgemm_kernel<128,1,0,0,1><<<dim3(12, 64), blk, 0, stream>>>(
      qkv_bf, src_bf, wqkv_bf, qkv_b, nullptr, M, 1536, 512);
  // 2. attention (bf16 in/out), QBLK=128 (reverted)
  attn_kernel<<<dim3(32, 16), blk, 0, stream>>>(attn_bf, qkv_bf);
  // 3. y = attn @ out_w^T + src   (fp32 out, fp32 residual), BN=64
  bgemm_kernel<64,0,0,1,0><<<dim3(8, 64), blk, 0, stream>>>(
      y, attn_bf, wout_bf, nullptr, src, M, 512, 512);
  // 4. x = LN1(y)  (fp32 + bf16)
  ln_kernel<1><<<dim3(M / 4), blk, 0, stream>>>(x, x_bf, y, ln1g, ln1b);
  // 5. h = relu(x @ w1^T + b1)  (bf16 out)
  bgemm_kernel<128,1,1,0,1><<<dim3(16, 64), blk, 0, stream>>>(
      h_bf, x_bf, w1_bf, b1, nullptr, M, 2048, 512);
  // 6. z = h @ w2^T + b2 + x  (fp32 out), BN=64
  bgemm_kernel<64,1,0,1,0><<<dim3(8, 64), blk, 0, stream>>>(
      z, h_bf, w2_bf, b2, x, M, 512, 2048);
  // 7. out = LN2(z)
  ln_kernel<0><<<dim3(M / 4), blk, 0, stream>>>(out, nullptr, z, ln2g, ln2b);
}

// Round 10
// 323.882 us; speedup vs baseline: 1.0388x; 1.0388x over previous
//
#include <hip/hip_runtime.h>
#include <cstdint>
#include <math.h>

#define CF4(p) (*reinterpret_cast<const float4*>(p))
#define F4(p)  (*reinterpret_cast<float4*>(p))

typedef __attribute__((ext_vector_type(8))) short bf16x8;
typedef __attribute__((ext_vector_type(4))) float f32x4;

__device__ __forceinline__ unsigned short f2bf(float x) {
  union { float f; unsigned int u; } v; v.f = x;
  unsigned int r = v.u + 0x7FFF + ((v.u >> 16) & 1);
  return (unsigned short)(r >> 16);
}

// swizzled LDS element index for [row][64 bf16] tiles (128B rows):
// elem col ^= ((row&7)<<3)  <=>  byte ^= ((row&7)<<4)
__device__ __forceinline__ int swz(int row, int col) {
  return row * 64 + (col ^ ((row & 7) << 3));
}

__device__ __forceinline__ void gload_lds16(const void* g, void* lds) {
  __builtin_amdgcn_global_load_lds(
      (const __attribute__((address_space(1))) void*)g,
      (__attribute__((address_space(3))) void*)lds, 16, 0, 0);
}

// ---------------------------------------------------------------------------
// fused fp32 -> bf16 convert for all 5 tensors (1 launch)
// ---------------------------------------------------------------------------
__global__ __launch_bounds__(256) void cvt_all_kernel(
    const float* __restrict__ src,   unsigned short* __restrict__ src_bf,
    const float* __restrict__ qkvw,  unsigned short* __restrict__ qkvw_bf,
    const float* __restrict__ outw,  unsigned short* __restrict__ outw_bf,
    const float* __restrict__ w1,    unsigned short* __restrict__ w1_bf,
    const float* __restrict__ w2,    unsigned short* __restrict__ w2_bf)
{
  int i = blockIdx.x * 256 + threadIdx.x;
  const float* s; unsigned short* d;
  if      (i < 524288) { s = src;  d = src_bf;                        }
  else if (i < 622592) { s = qkvw; d = qkvw_bf; i -= 524288;          }
  else if (i < 655360) { s = outw; d = outw_bf; i -= 622592;          }
  else if (i < 786432) { s = w1;   d = w1_bf;   i -= 655360;          }
  else if (i < 917504) { s = w2;   d = w2_bf;   i -= 786432;          }
  else return;
  float4 a = CF4(&s[i * 8]), b = CF4(&s[i * 8 + 4]);
  union { bf16x8 v; unsigned short u[8]; } w;
  w.u[0] = f2bf(a.x); w.u[1] = f2bf(a.y); w.u[2] = f2bf(a.z); w.u[3] = f2bf(a.w);
  w.u[4] = f2bf(b.x); w.u[5] = f2bf(b.y); w.u[6] = f2bf(b.z); w.u[7] = f2bf(b.w);
  *reinterpret_cast<bf16x8*>(&d[i * 8]) = w.v;
}

// ---------------------------------------------------------------------------
// bf16 MFMA GEMM, tile 128 x BNT, double-buffered LDS, 2-deep prefetch with
// COUNTED vmcnt (T3/T4): loads for tile kt+1 stay in flight across the
// barrier; vmcnt(VM) waits only for tile kt. vmcnt(0) only at last iter.
// Orientation/epilogue = R8 (coalesced column stores; C^T swap regressed).
// ---------------------------------------------------------------------------
template<int BNT, int BIAS, int RELU, int RES, int OBF>
__global__ __launch_bounds__(256, 2) void bgemm_kernel(
    void* __restrict__ Cv, const unsigned short* __restrict__ A,
    const unsigned short* __restrict__ W, const float* __restrict__ bias,
    const float* __restrict__ R, int M, int N, int K)
{
  constexpr int NJ = BNT / 32;
  constexpr int VM = 4 + BNT / 32;   // per-thread gload_lds per tile
  __shared__ __align__(16) unsigned short As[2][128 * 64];
  __shared__ __align__(16) unsigned short Ws[2][BNT * 64];

  const int t    = threadIdx.x;
  const int lane = t & 63, wid = t >> 6;
  const int g    = lane >> 4, lr = lane & 15;
  const int wm   = wid >> 1,  wn = wid & 1;
  const int m0   = blockIdx.y * 128, n0 = blockIdx.x * BNT;

  const int sr8 = lane >> 3;
  const int sc  = (lane & 7) ^ sr8;
  const unsigned short* Ag = A + (size_t)(m0 + sr8) * K + sc * 8;
  const unsigned short* Wg = W + (size_t)(n0 + sr8) * K + sc * 8;

  f32x4 acc[4][NJ];
#pragma unroll
  for (int mi = 0; mi < 4; ++mi)
#pragma unroll
    for (int nj = 0; nj < NJ; ++nj)
      acc[mi][nj] = (f32x4){0.f, 0.f, 0.f, 0.f};

#define STAGE_G(buf, k0)                                                   \
  {                                                                        \
    _Pragma("unroll")                                                      \
    for (int i = 0; i < 4; ++i) {                                          \
      const int rb = wid * 32 + i * 8;                                     \
      gload_lds16(Ag + (size_t)rb * K + (k0), (void*)&As[buf][rb * 64]);   \
    }                                                                      \
    _Pragma("unroll")                                                      \
    for (int i = 0; i < BNT / 32; ++i) {                                   \
      const int rb = wid * (BNT / 4) + i * 8;                              \
      gload_lds16(Wg + (size_t)rb * K + (k0), (void*)&Ws[buf][rb * 64]);   \
    }                                                                      \
  }

  const int nk = K >> 6;
  STAGE_G(0, 0);
  STAGE_G(1, 64);

  for (int kt = 0; kt < nk; ++kt) {
    const int cur = kt & 1;
    // wait for tile kt's loads only; kt+1's stay in flight
    if (kt + 1 < nk) {
      asm volatile("s_waitcnt vmcnt(%0)" :: "i"(VM) : "memory");
    } else {
      asm volatile("s_waitcnt vmcnt(0)" ::: "memory");
    }
    __builtin_amdgcn_s_barrier();

#pragma unroll
    for (int ks = 0; ks < 2; ++ks) {
      bf16x8 af[4], bfr[NJ];
#pragma unroll
      for (int mi = 0; mi < 4; ++mi) {
        const int row = wm * 64 + mi * 16 + lr;
        af[mi] = *reinterpret_cast<const bf16x8*>(
            &As[cur][row * 64 + (((ks * 4 + g) ^ (row & 7)) * 8)]);
      }
#pragma unroll
      for (int nj = 0; nj < NJ; ++nj) {
        const int row = wn * (BNT / 2) + nj * 16 + lr;
        bfr[nj] = *reinterpret_cast<const bf16x8*>(
            &Ws[cur][row * 64 + (((ks * 4 + g) ^ (row & 7)) * 8)]);
      }
#pragma unroll
      for (int mi = 0; mi < 4; ++mi)
#pragma unroll
        for (int nj = 0; nj < NJ; ++nj)
          acc[mi][nj] = __builtin_amdgcn_mfma_f32_16x16x32_bf16(
              af[mi], bfr[nj], acc[mi][nj], 0, 0, 0);
    }

    __builtin_amdgcn_s_barrier();   // all reads of buf[cur] done
    if (kt + 2 < nk) STAGE_G(cur, (kt + 2) * 64);
  }
#undef STAGE_G

  // epilogue (R8 orientation): r = ..+g*4+reg, c = ..+nj*16+lr (coalesced)
#pragma unroll
  for (int mi = 0; mi < 4; ++mi) {
#pragma unroll
    for (int reg = 0; reg < 4; ++reg) {
      const int r = m0 + wm * 64 + mi * 16 + g * 4 + reg;
#pragma unroll
      for (int nj = 0; nj < NJ; ++nj) {
        const int cc = n0 + wn * (BNT / 2) + nj * 16 + lr;
        float v = acc[mi][nj][reg];
        if (BIAS) v += bias[cc];
        if (RES)  v += R[(size_t)r * N + cc];
        if (RELU) v = fmaxf(v, 0.f);
        if (OBF)  ((unsigned short*)Cv)[(size_t)r * N + cc] = f2bf(v);
        else      ((float*)Cv)[(size_t)r * N + cc] = v;
      }
    }
  }
}

// ---------------------------------------------------------------------------
// Flash attention: unchanged from R9 (121.3 us verified).
// ---------------------------------------------------------------------------
__global__ __launch_bounds__(256, 2) void attn_kernel(
    unsigned short* __restrict__ O, const unsigned short* __restrict__ qkv)
{
  const int Bb = 2, LD = 1536, DM = 512;
  const int qt = blockIdx.x;
  const int nh = blockIdx.y;
  const int b = nh >> 3, h = nh & 7;
  const int cq = h * 64, ck = 512 + h * 64, cv = 1024 + h * 64;

  __shared__ __align__(16) unsigned short Ks [2][64 * 64];
  __shared__ __align__(16) unsigned short Vts[2][64 * 64];
  __shared__ __align__(16) unsigned short Ps [128 * 64];

  const int t    = threadIdx.x;
  const int lane = t & 63;
  const int wid  = t >> 6;
  const int g    = lane >> 4;
  const int lr   = lane & 15;
  const int wq0  = wid * 32;

  bf16x8 qf[2][2];
#pragma unroll
  for (int mi = 0; mi < 2; ++mi)
#pragma unroll
    for (int kq = 0; kq < 2; ++kq)
      qf[mi][kq] = *reinterpret_cast<const bf16x8*>(
          &qkv[((size_t)(qt * 128 + wq0 + mi * 16 + lr) * Bb + b) * LD
               + cq + kq * 32 + g * 8]);

  f32x4 o_acc[2][4];
  float lsum[2] = {0.f, 0.f};
#pragma unroll
  for (int mi = 0; mi < 2; ++mi)
#pragma unroll
    for (int dj = 0; dj < 4; ++dj)
      o_acc[mi][dj] = (f32x4){0.f, 0.f, 0.f, 0.f};

  const int sr8 = lane >> 3;
  const int scK = (lane & 7) ^ sr8;
  const int vD0 = wid * 8;
  const int vSr = lane;

#define STAGE_K(buf, kt)                                               \
  {                                                                    \
    _Pragma("unroll")                                                  \
    for (int i = 0; i < 2; ++i) {                                      \
      const int rb = wid * 16 + i * 8;                                 \
      gload_lds16(&qkv[((size_t)((kt) * 64 + rb + sr8) * Bb + b) * LD  \
                       + ck + scK * 8],                                \
                  (void*)&Ks[buf][rb * 64]);                           \
    }                                                                  \
  }
#define LOAD_V(kt)                                                     \
  {                                                                    \
    _Pragma("unroll")                                                  \
    for (int p = 0; p < 2; ++p)                                        \
      vr[p] = *reinterpret_cast<const bf16x8*>(                        \
          &qkv[((size_t)((kt) * 64 + vSr) * Bb + b) * LD + cv          \
               + vD0 + p * 32]);                                       \
  }
#define WRITE_V(buf)                                                   \
  {                                                                    \
    _Pragma("unroll")                                                  \
    for (int p = 0; p < 2; ++p) {                                      \
      const int d0 = vD0 + p * 32;                                     \
      union { bf16x8 v; unsigned short u[8]; } w;                      \
      w.v = vr[p];                                                     \
      _Pragma("unroll")                                                \
      for (int j = 0; j < 8; ++j)                                      \
        Vts[buf][swz(d0 + j, vSr)] = w.u[j];                           \
    }                                                                  \
  }

  bf16x8 vr[2];
  STAGE_K(0, 0);
  LOAD_V(0);
  WRITE_V(0);
  __syncthreads();

  for (int kt = 0; kt < 64; ++kt) {
    const int cur = kt & 1;
    const bool hasNext = (kt < 63);
    if (hasNext) { STAGE_K(cur ^ 1, kt + 1); LOAD_V(kt + 1); }

    f32x4 sfT[2][4];
#pragma unroll
    for (int mi = 0; mi < 2; ++mi)
#pragma unroll
      for (int nj = 0; nj < 4; ++nj)
        sfT[mi][nj] = (f32x4){0.f, 0.f, 0.f, 0.f};
    __builtin_amdgcn_s_setprio(1);
#pragma unroll
    for (int nj = 0; nj < 4; ++nj) {
#pragma unroll
      for (int kq = 0; kq < 2; ++kq) {
        bf16x8 ak = *reinterpret_cast<const bf16x8*>(
            &Ks[cur][swz(nj * 16 + lr, kq * 32 + g * 8)]);
        sfT[0][nj] = __builtin_amdgcn_mfma_f32_16x16x32_bf16(
            ak, qf[0][kq], sfT[0][nj], 0, 0, 0);
        sfT[1][nj] = __builtin_amdgcn_mfma_f32_16x16x32_bf16(
            ak, qf[1][kq], sfT[1][nj], 0, 0, 0);
      }
    }
    __builtin_amdgcn_s_setprio(0);

#pragma unroll
    for (int mi = 0; mi < 2; ++mi) {
      const int qrow = wq0 + mi * 16 + lr;
#pragma unroll
      for (int nj = 0; nj < 4; ++nj) {
        const float p0 = __expf(sfT[mi][nj][0]);
        const float p1 = __expf(sfT[mi][nj][1]);
        const float p2 = __expf(sfT[mi][nj][2]);
        const float p3 = __expf(sfT[mi][nj][3]);
        lsum[mi] += (p0 + p1) + (p2 + p3);
        unsigned int w0, w1;
        asm("v_cvt_pk_bf16_f32 %0, %1, %2" : "=v"(w0) : "v"(p0), "v"(p1));
        asm("v_cvt_pk_bf16_f32 %0, %1, %2" : "=v"(w1) : "v"(p2), "v"(p3));
        *reinterpret_cast<uint2*>(&Ps[swz(qrow, nj * 16 + g * 4)]) =
            make_uint2(w0, w1);
      }
    }

    __builtin_amdgcn_s_setprio(1);
#pragma unroll
    for (int kks = 0; kks < 2; ++kks) {
      bf16x8 pa0 = *reinterpret_cast<const bf16x8*>(
          &Ps[swz(wq0 +  0 + lr, kks * 32 + g * 8)]);
      bf16x8 pa1 = *reinterpret_cast<const bf16x8*>(
          &Ps[swz(wq0 + 16 + lr, kks * 32 + g * 8)]);
#pragma unroll
      for (int dj = 0; dj < 4; ++dj) {
        bf16x8 vb = *reinterpret_cast<const bf16x8*>(
            &Vts[cur][swz(dj * 16 + lr, kks * 32 + g * 8)]);
        o_acc[0][dj] = __builtin_amdgcn_mfma_f32_16x16x32_bf16(
            pa0, vb, o_acc[0][dj], 0, 0, 0);
        o_acc[1][dj] = __builtin_amdgcn_mfma_f32_16x16x32_bf16(
            pa1, vb, o_acc[1][dj], 0, 0, 0);
      }
    }
    __builtin_amdgcn_s_setprio(0);

    if (hasNext) WRITE_V(cur ^ 1);
    __syncthreads();
  }
#undef STAGE_K
#undef LOAD_V
#undef WRITE_V

#pragma unroll
  for (int mi = 0; mi < 2; ++mi) {
    float rs = lsum[mi];
    rs += __shfl_xor(rs, 16);
    rs += __shfl_xor(rs, 32);
#pragma unroll
    for (int reg = 0; reg < 4; ++reg) {
      const float rsq = __shfl(rs, (lane & 48) + g * 4 + reg);
      const float inv = 1.f / rsq;
      const int q = qt * 128 + wq0 + mi * 16 + g * 4 + reg;
#pragma unroll
      for (int dj = 0; dj < 4; ++dj)
        O[((size_t)q * Bb + b) * DM + h * 64 + dj * 16 + lr] =
            f2bf(o_acc[mi][dj][reg] * inv);
    }
  }
}

// ---------------------------------------------------------------------------
// LayerNorm D=512; optional bf16 side output
// ---------------------------------------------------------------------------
template<int WBF>
__global__ __launch_bounds__(256) void ln_kernel(
    float* __restrict__ out, unsigned short* __restrict__ obf,
    const float* __restrict__ in, const float* __restrict__ g,
    const float* __restrict__ bb)
{
  const int w = threadIdx.x >> 6, lane = threadIdx.x & 63;
  const size_t row = (size_t)blockIdx.x * 4 + w;
  const float* xr = in + row * 512;
  float4 v0 = CF4(&xr[lane * 4]);
  float4 v1 = CF4(&xr[256 + lane * 4]);
  float s = v0.x + v0.y + v0.z + v0.w + v1.x + v1.y + v1.z + v1.w;
  float q = v0.x*v0.x + v0.y*v0.y + v0.z*v0.z + v0.w*v0.w
          + v1.x*v1.x + v1.y*v1.y + v1.z*v1.z + v1.w*v1.w;
#pragma unroll
  for (int off = 1; off < 64; off <<= 1) {
    s += __shfl_xor(s, off);
    q += __shfl_xor(q, off);
  }
  const float mu  = s * (1.f / 512.f);
  const float var = q * (1.f / 512.f) - mu * mu;
  const float rst = rsqrtf(var + 1e-5f);
  float4 g0 = CF4(&g[lane * 4]),  g1 = CF4(&g[256 + lane * 4]);
  float4 b0 = CF4(&bb[lane * 4]), b1 = CF4(&bb[256 + lane * 4]);
  float* orow = out + row * 512;
  float4 o0, o1;
  o0.x = (v0.x - mu) * rst * g0.x + b0.x;
  o0.y = (v0.y - mu) * rst * g0.y + b0.y;
  o0.z = (v0.z - mu) * rst * g0.z + b0.z;
  o0.w = (v0.w - mu) * rst * g0.w + b0.w;
  o1.x = (v1.x - mu) * rst * g1.x + b1.x;
  o1.y = (v1.y - mu) * rst * g1.y + b1.y;
  o1.z = (v1.z - mu) * rst * g1.z + b1.z;
  o1.w = (v1.w - mu) * rst * g1.w + b1.w;
  F4(&orow[lane * 4]) = o0;
  F4(&orow[256 + lane * 4]) = o1;
  if (WBF) {
    unsigned short* brow = obf + row * 512;
    ushort4 u0 = make_ushort4(f2bf(o0.x), f2bf(o0.y), f2bf(o0.z), f2bf(o0.w));
    ushort4 u1 = make_ushort4(f2bf(o1.x), f2bf(o1.y), f2bf(o1.z), f2bf(o1.w));
    *reinterpret_cast<ushort4*>(&brow[lane * 4]) = u0;
    *reinterpret_cast<ushort4*>(&brow[256 + lane * 4]) = u1;
  }
}

// ---------------------------------------------------------------------------
extern "C" void kernel_launch(void* const* d_in, const int* in_sizes, int n_in,
                              void* d_out, int out_size, void* d_ws, size_t ws_size,
                              hipStream_t stream)
{
  const float* src   = (const float*)d_in[0];
  const float* qkv_w = (const float*)d_in[1];
  const float* qkv_b = (const float*)d_in[2];
  const float* out_w = (const float*)d_in[3];
  const float* w1    = (const float*)d_in[4];
  const float* b1    = (const float*)d_in[5];
  const float* w2    = (const float*)d_in[6];
  const float* b2    = (const float*)d_in[7];
  const float* ln1g  = (const float*)d_in[8];
  const float* ln1b  = (const float*)d_in[9];
  const float* ln2g  = (const float*)d_in[10];
  const float* ln2b  = (const float*)d_in[11];
  float* out = (float*)d_out;

  const int M = 8192;

  char* ws = (char*)d_ws;
  unsigned short* qkv_bf  = (unsigned short*)(ws + 0);         // 25165824
  unsigned short* attn_bf = (unsigned short*)(ws + 25165824);  //  8388608
  unsigned short* h_bf    = (unsigned short*)(ws + 0);         // 33554432 (reuse)
  float*          y       = (float*)(ws + 33554432);           // 16777216
  float*          z       = (float*)(ws + 33554432);           // (reuse y)
  float*          x       = (float*)(ws + 50331648);           // 16777216
  unsigned short* x_bf    = (unsigned short*)(ws + 67108864);  //  8388608
  unsigned short* src_bf  = (unsigned short*)(ws + 75497472);  //  8388608
  unsigned short* wqkv_bf = (unsigned short*)(ws + 83886080);  //  1572864
  unsigned short* wout_bf = (unsigned short*)(ws + 85458944);  //   524288
  unsigned short* w1_bf   = (unsigned short*)(ws + 85983232);  //  2097152
  unsigned short* w2_bf   = (unsigned short*)(ws + 88080384);  //  2097152
  if (ws_size < (size_t)90177536) return;

  dim3 blk(256);

  // 0. all fp32 -> bf16 conversions (1 launch)
  cvt_all_kernel<<<dim3(3584), blk, 0, stream>>>(
      src, src_bf, qkv_w, wqkv_bf, out_w, wout_bf, w1, w1_bf, w2, w2_bf);

  // 1. qkv = src @ qkv_w^T + qkv_b   (bf16 out)
  bgemm_kernel<128,1,0,0,1><<<dim3(12, 64), blk, 0, stream>>>(
      qkv_bf, src_bf, wqkv_bf, qkv_b, nullptr, M, 1536, 512);
  // 2. attention (bf16 in/out)
  attn_kernel<<<dim3(32, 16), blk, 0, stream>>>(attn_bf, qkv_bf);
  // 3. y = attn @ out_w^T + src   (fp32 out, fp32 residual), BN=64
  bgemm_kernel<64,0,0,1,0><<<dim3(8, 64), blk, 0, stream>>>(
      y, attn_bf, wout_bf, nullptr, src, M, 512, 512);
  // 4. x = LN1(y)  (fp32 + bf16)
  ln_kernel<1><<<dim3(M / 4), blk, 0, stream>>>(x, x_bf, y, ln1g, ln1b);
  // 5. h = relu(x @ w1^T + b1)  (bf16 out)
  bgemm_kernel<128,1,1,0,1><<<dim3(16, 64), blk, 0, stream>>>(
      h_bf, x_bf, w1_bf, b1, nullptr, M, 2048, 512);
  // 6. z = h @ w2^T + b2 + x  (fp32 out), BN=64
  bgemm_kernel<64,1,0,1,0><<<dim3(8, 64), blk, 0, stream>>>(
      z, h_bf, w2_bf, b2, x, M, 512, 2048);
  // 7. out = LN2(z)
  ln_kernel<0><<<dim3(M / 4), blk, 0, stream>>>(out, nullptr, z, ln2g, ln2b);
}